// Round 8
// baseline (658.562 us; speedup 1.0000x reference)
//
#include <hip/hip_runtime.h>
#include <hip/hip_bf16.h>
#include <math.h>

// Problem constants (B=2, S=2048, D=1024, H=16, DH=64, FF=4096)
#define BB 2
#define SS 2048
#define DD 1024
#define HH 16
#define DHD 64
#define FFD 4096
#define NROWS (BB*SS)
#define QLD 3072   // interleaved QKV row stride

typedef __bf16 bf16_t;
typedef __bf16 bf16x8 __attribute__((ext_vector_type(8)));
typedef float floatx4 __attribute__((ext_vector_type(4)));

union FragU { uint4 u; bf16x8 v; bf16_t e[8]; };
union U4v  { uint2 u; bf16_t e[4]; };

static __device__ __forceinline__ bf16x8 ld_frag16(const bf16_t* p) {
  FragU f; f.u = *reinterpret_cast<const uint4*>(p); return f.v;
}

// async global->LDS 16B: lane i of the wave lands at lptr + i*16 (wave-uniform base!)
static __device__ __forceinline__ void gl_lds16(const bf16_t* g, bf16_t* l) {
  __builtin_amdgcn_global_load_lds(
      (const __attribute__((address_space(1))) unsigned int*)g,
      (__attribute__((address_space(3))) unsigned int*)l, 16, 0, 0);
}

// flag-dependent scalar read of a "float param" tensor (f32 or bf16)
static __device__ __forceinline__ float ld_param(const void* p, int i, int f32m) {
  return f32m ? ((const float*)p)[i] : (float)((const bf16_t*)p)[i];
}

// ---------------------------------------------------------------------------
// Detector: flags[0]=1 if float tensors are really f32; flags[1]=1 if masks int8.
// ---------------------------------------------------------------------------
__global__ __launch_bounds__(256) void detect_k(const void* __restrict__ xp,
                                                const void* __restrict__ ep,
                                                const void* __restrict__ wp,
                                                const int* __restrict__ mk,
                                                int* __restrict__ flags) {
  const int t = threadIdx.x;
  const unsigned short* a = (const unsigned short*)xp;
  const unsigned short* b = (const unsigned short*)ep;
  const unsigned short* c = (const unsigned short*)wp;
  int bad = 0, mbad = 0;
  for (int i = t; i < 4096; i += 256) {
    int e1 = (a[i] >> 7) & 0xFF, e2 = (b[i] >> 7) & 0xFF, e3 = (c[i] >> 7) & 0xFF;
    if (e1 >= 0x9B || e2 >= 0x9B || e3 >= 0x9B) bad = 1;
  }
  for (int i = t; i < 1024; i += 256) {
    unsigned v = (unsigned)mk[i];
    if (v > 1u) mbad = 1;
  }
  __shared__ int s0, s1;
  if (t == 0) { s0 = 0; s1 = 0; }
  __syncthreads();
  if (bad)  atomicOr(&s0, 1);
  if (mbad) atomicOr(&s1, 1);
  __syncthreads();
  if (t == 0) { flags[0] = s0; flags[1] = s1; }
}

// ---------------------------------------------------------------------------
// Canonicalize a float tensor to bf16 (copy if already bf16). Vectorized 8/thread.
// ---------------------------------------------------------------------------
__global__ __launch_bounds__(256) void cvt_k(const void* __restrict__ src,
                                             bf16_t* __restrict__ dst, int n,
                                             const int* __restrict__ flg) {
  const int f32m = flg[0];
  const int idx = blockIdx.x * 256 + threadIdx.x;
  const int stride = gridDim.x * 256;
  const int n8 = n >> 3;
  if (f32m) {
    const float4* s = (const float4*)src;
    for (int i = idx; i < n8; i += stride) {
      float4 a = s[2 * i], b = s[2 * i + 1];
      FragU f;
      f.e[0] = (bf16_t)a.x; f.e[1] = (bf16_t)a.y; f.e[2] = (bf16_t)a.z; f.e[3] = (bf16_t)a.w;
      f.e[4] = (bf16_t)b.x; f.e[5] = (bf16_t)b.y; f.e[6] = (bf16_t)b.z; f.e[7] = (bf16_t)b.w;
      *reinterpret_cast<uint4*>(dst + (size_t)i * 8) = f.u;
    }
  } else {
    const uint4* s = (const uint4*)src;
    uint4* d = (uint4*)dst;
    for (int i = idx; i < n8; i += stride) d[i] = s[i];
  }
}

// ---------------------------------------------------------------------------
// Transpose core (shared by single & batched kernels).
// ---------------------------------------------------------------------------
static __device__ __forceinline__ void transpose_body(const void* inv, bf16_t* out,
                                                      int rows, int cols, int f32m) {
  __shared__ __align__(16) bf16_t tile[64][72];
  const int c0 = blockIdx.x * 64, r0 = blockIdx.y * 64;
  const int t  = threadIdx.x;
  const int lr = t >> 3;            // 0..31
  const int lc = (t & 7) * 8;       // 0..56
#pragma unroll
  for (int half = 0; half < 2; ++half) {
    int r = lr + half * 32;
    if (f32m) {
      const float* p = (const float*)inv + (size_t)(r0 + r) * cols + c0 + lc;
      float4 q0 = *reinterpret_cast<const float4*>(p);
      float4 q1 = *reinterpret_cast<const float4*>(p + 4);
      tile[r][lc+0] = (bf16_t)q0.x; tile[r][lc+1] = (bf16_t)q0.y;
      tile[r][lc+2] = (bf16_t)q0.z; tile[r][lc+3] = (bf16_t)q0.w;
      tile[r][lc+4] = (bf16_t)q1.x; tile[r][lc+5] = (bf16_t)q1.y;
      tile[r][lc+6] = (bf16_t)q1.z; tile[r][lc+7] = (bf16_t)q1.w;
    } else {
      uint4 vv = *reinterpret_cast<const uint4*>((const bf16_t*)inv + (size_t)(r0 + r) * cols + c0 + lc);
      *reinterpret_cast<uint4*>(&tile[r][lc]) = vv;
    }
  }
  __syncthreads();
#pragma unroll
  for (int half = 0; half < 2; ++half) {
    int oc = lr + half * 32;
    FragU f;
#pragma unroll
    for (int j = 0; j < 8; ++j) f.e[j] = tile[lc + j][oc];
    *reinterpret_cast<uint4*>(out + (size_t)(c0 + oc) * rows + r0 + lc) = f.u;
  }
}

__global__ __launch_bounds__(256) void transpose_k(const void* __restrict__ inv,
                                                   bf16_t* __restrict__ out,
                                                   int rows, int cols,
                                                   const int* __restrict__ flg) {
  transpose_body(inv, out, rows, cols, flg[0]);
}

struct Ptr4 { const void* p0; const void* p1; const void* p2; const void* p3; };

// 4 D x D transposes in one launch: grid (16,16,4)
__global__ __launch_bounds__(256) void transpose4_k(Ptr4 in, bf16_t* __restrict__ out,
                                                    const int* __restrict__ flg) {
  const void* src = (blockIdx.z == 0) ? in.p0 : (blockIdx.z == 1) ? in.p1
                   : (blockIdx.z == 2) ? in.p2 : in.p3;
  transpose_body(src, out + (size_t)blockIdx.z * DD * DD, DD, DD, flg[0]);
}

// ---------------------------------------------------------------------------
// gemm64: 64x128 tile, the ONLY GEMM kernel (r8). C[M,N] = A @ Bt^T (+bias/GELU).
// Rationale: r6 proved 64-row tiles beat 128^2 at N=1024 (2/CU vs 1/CU);
// r7 counters showed the remaining 128^2 gemm_nt latency-bound (MfmaUtil 9%,
// Occ 28%). 64x128 gives QKV 1536 blocks = 6/CU, fc1 2048 = 8/CU.
// 4 waves as 2M x 2N, per-wave 32x64 (acc[2][4]). LDS 12 KiB.
// A2/nsplit: blocks with n0>=nsplit read A2 (cross-attn QKV fusion).
// ---------------------------------------------------------------------------
template<int BIAS, int GELU>
__global__ __launch_bounds__(256) void gemm64(const bf16_t* __restrict__ A,
                                              const bf16_t* __restrict__ A2,
                                              int nsplit,
                                              const bf16_t* __restrict__ Bt,
                                              const void* __restrict__ bias,
                                              bf16_t* __restrict__ C,
                                              int M, int N, int K, int ldc,
                                              const int* __restrict__ flg) {
  __shared__ __align__(16) bf16_t As[64 * 32];
  __shared__ __align__(16) bf16_t Bs[128 * 32];
  const int m0 = blockIdx.y * 64, n0 = blockIdx.x * 128;
  const bf16_t* Ap = (A2 != nullptr && n0 >= nsplit) ? A2 : A;
  const int t = threadIdx.x, lane = t & 63, w = t >> 6;
  const int quad = lane >> 4, l16 = lane & 15;
  const int wy = w >> 1, wx = w & 1;

  floatx4 acc[2][4];
#pragma unroll
  for (int i = 0; i < 2; ++i)
#pragma unroll
    for (int j = 0; j < 4; ++j) { floatx4 z = {0.f,0.f,0.f,0.f}; acc[i][j] = z; }

  const int srow = lane >> 2;
  const int scol = (lane & 3) * 8;

  for (int k0 = 0; k0 < K; k0 += 32) {
    __syncthreads();
    gl_lds16(Ap + (size_t)(m0 + w * 16 + srow) * K + k0 + scol, As + w * 512);
#pragma unroll
    for (int c = 0; c < 2; ++c) {
      const int chunk = w * 2 + c;
      gl_lds16(Bt + (size_t)(n0 + chunk * 16 + srow) * K + k0 + scol, Bs + chunk * 512);
    }
    __syncthreads();

    bf16x8 af[2], bfr[4];
#pragma unroll
    for (int mt = 0; mt < 2; ++mt) af[mt]  = ld_frag16(As + (wy*32 + mt*16 + l16) * 32 + quad*8);
#pragma unroll
    for (int nt = 0; nt < 4; ++nt) bfr[nt] = ld_frag16(Bs + (wx*64 + nt*16 + l16) * 32 + quad*8);
#pragma unroll
    for (int mt = 0; mt < 2; ++mt)
#pragma unroll
      for (int nt = 0; nt < 4; ++nt)
        acc[mt][nt] = __builtin_amdgcn_mfma_f32_16x16x32_bf16(af[mt], bfr[nt], acc[mt][nt], 0, 0, 0);
  }

  const int f32m = BIAS ? flg[0] : 0;
#pragma unroll
  for (int nt = 0; nt < 4; ++nt) {
    const int c = n0 + wx*64 + nt*16 + l16;
    float bv = 0.f;
    if (BIAS) bv = ld_param(bias, c, f32m);
#pragma unroll
    for (int mt = 0; mt < 2; ++mt) {
      const int rb = m0 + wy*32 + mt*16 + quad*4;
#pragma unroll
      for (int reg = 0; reg < 4; ++reg) {
        float v2 = acc[mt][nt][reg] + bv;
        if (GELU) v2 = 0.5f * v2 * (1.f + erff(v2 * 0.70710678118654752f));
        C[(size_t)(rb + reg) * ldc + c] = (bf16_t)v2;
      }
    }
  }
}

// ---------------------------------------------------------------------------
// MFMA flash attention, 64-key tiles, QBLK=128.
// QKV interleaved [B*S, 3072] (Q|K|V). grid (S/128, B*H) = 512 blocks = 2/CU.
// 4 waves x 32 q-rows (two 16-row groups mh=0,1): each K/V fragment read from
// LDS feeds TWO MFMAs. Static-max softmax (-8), Ps chunk-swizzled.
// ---------------------------------------------------------------------------
__global__ __launch_bounds__(256, 2) void attn_k(const bf16_t* __restrict__ QKV,
                                                 const int* __restrict__ mask,
                                                 bf16_t* __restrict__ O,
                                                 const int* __restrict__ flg) {
  __shared__ __align__(16) bf16_t Ks[64 * 72];    // [key][dh] stride 72
  __shared__ __align__(16) bf16_t Vt[64 * 72];    // [dh][key, chunk-swizzled]
  __shared__ __align__(16) bf16_t Ps[4][32 * 72]; // per-wave P [qrow][key], chunk-swizzled
  __shared__ bf16_t msk[SS];                      // additive mask row (-8 / -1e30)
  const int mflag = flg[1];
  const int b = blockIdx.y >> 4, h = blockIdx.y & 15;
  const int s0 = blockIdx.x * 128;
  const int t = threadIdx.x, w = t >> 6, lane = t & 63;
  const int quad = lane >> 4, l16 = lane & 15;
  const float L2S = 0.18033688011112042f;   // 0.125 * log2(e)

  for (int j = t; j < SS; j += 256) {
    const int mv = mflag ? (int)((const signed char*)mask)[b * SS + j] : mask[b * SS + j];
    msk[j] = (bf16_t)(mv ? -1.0e30f : -8.0f);
  }

  // Q A-fragments for both 16-row groups
  bf16x8 qf[2][2];
#pragma unroll
  for (int mh = 0; mh < 2; ++mh) {
    const int r = s0 + w * 32 + mh * 16 + l16;
    const bf16_t* qp = QKV + (size_t)(b * SS + r) * QLD + h * DHD;
#pragma unroll
    for (int kq = 0; kq < 2; ++kq) qf[mh][kq] = ld_frag16(qp + kq * 32 + quad * 8);
  }

  bf16x8 ones;
#pragma unroll
  for (int j = 0; j < 8; ++j) ones[j] = (bf16_t)1.0f;

  floatx4 accO[2][4], accl[2];
  { floatx4 z = {0.f,0.f,0.f,0.f};
#pragma unroll
    for (int mh = 0; mh < 2; ++mh) { accl[mh] = z;
#pragma unroll
      for (int i = 0; i < 4; ++i) accO[mh][i] = z; } }

  const int krow = t >> 2, kc = (t & 3) * 16;
  const int vkey = t & 63, vw16 = (t >> 6) * 16;
  const int vq = vkey >> 3, vk7 = vkey & 7;
  const int vs0 = (vw16 >> 3) & 7, vs1 = (vs0 + 1) & 7;

  int coff[4];
#pragma unroll
  for (int cf = 0; cf < 4; ++cf)
    coff[cf] = (((((cf << 1) | (l16 >> 3))) ^ ((quad >> 1) << 1)) << 3) + (l16 & 7);
  const int rsw = ((l16 >> 3) & 1) << 1;

  const bf16_t* kp = QKV + 1024 + (size_t)(b * SS + krow) * QLD + h * DHD + kc;
  const bf16_t* vp = QKV + 2048 + (size_t)(b * SS + vkey) * QLD + h * DHD + vw16;

  uint4 kr0 = *reinterpret_cast<const uint4*>(kp);
  uint4 kr1 = *reinterpret_cast<const uint4*>(kp + 8);
  uint4 vr0 = *reinterpret_cast<const uint4*>(vp);
  uint4 vr1 = *reinterpret_cast<const uint4*>(vp + 8);

  for (int j0 = 0; j0 < SS; j0 += 64) {
    __syncthreads();
    *reinterpret_cast<uint4*>(&Ks[krow * 72 + kc])     = kr0;
    *reinterpret_cast<uint4*>(&Ks[krow * 72 + kc + 8]) = kr1;
    { FragU v0; v0.u = vr0; FragU v1; v1.u = vr1;
#pragma unroll
      for (int j = 0; j < 8; ++j) Vt[(vw16 + j) * 72 + ((vq ^ vs0) << 3) + vk7] = v0.e[j];
#pragma unroll
      for (int j = 0; j < 8; ++j) Vt[(vw16 + 8 + j) * 72 + ((vq ^ vs1) << 3) + vk7] = v1.e[j];
    }
    __syncthreads();

    if (j0 + 64 < SS) {
      const bf16_t* kp2 = kp + (size_t)(j0 + 64) * QLD;
      const bf16_t* vp2 = vp + (size_t)(j0 + 64) * QLD;
      kr0 = *reinterpret_cast<const uint4*>(kp2);
      kr1 = *reinterpret_cast<const uint4*>(kp2 + 8);
      vr0 = *reinterpret_cast<const uint4*>(vp2);
      vr1 = *reinterpret_cast<const uint4*>(vp2 + 8);
    }

    // S = Q K^T : each Ks fragment feeds both mh groups
    floatx4 s4[2][4];
    { floatx4 z = {0.f,0.f,0.f,0.f};
#pragma unroll
      for (int mh = 0; mh < 2; ++mh)
#pragma unroll
        for (int cf = 0; cf < 4; ++cf) s4[mh][cf] = z; }
#pragma unroll
    for (int kq = 0; kq < 2; ++kq)
#pragma unroll
      for (int cf = 0; cf < 4; ++cf) {
        bf16x8 bf = ld_frag16(&Ks[(cf * 16 + l16) * 72 + kq * 32 + quad * 8]);
#pragma unroll
        for (int mh = 0; mh < 2; ++mh)
          s4[mh][cf] = __builtin_amdgcn_mfma_f32_16x16x32_bf16(qf[mh][kq], bf, s4[mh][cf], 0, 0, 0);
      }
    float ml[4];
#pragma unroll
    for (int cf = 0; cf < 4; ++cf) ml[cf] = (float)msk[j0 + cf * 16 + l16];

    // static-max softmax for both groups
#pragma unroll
    for (int mh = 0; mh < 2; ++mh)
#pragma unroll
      for (int reg = 0; reg < 4; ++reg) {
        const float p0 = exp2f(fmaf(s4[mh][0][reg], L2S, ml[0]));
        const float p1 = exp2f(fmaf(s4[mh][1][reg], L2S, ml[1]));
        const float p2 = exp2f(fmaf(s4[mh][2][reg], L2S, ml[2]));
        const float p3 = exp2f(fmaf(s4[mh][3][reg], L2S, ml[3]));
        const int rb = (mh * 16 + quad * 4 + reg) * 72;
        Ps[w][rb + coff[0]] = (bf16_t)p0;
        Ps[w][rb + coff[1]] = (bf16_t)p1;
        Ps[w][rb + coff[2]] = (bf16_t)p2;
        Ps[w][rb + coff[3]] = (bf16_t)p3;
      }
    asm volatile("s_waitcnt lgkmcnt(0)" ::: "memory");

    // O += P V ; l += P 1 : each Vt fragment feeds both mh groups
    bf16x8 pa[2][2];
#pragma unroll
    for (int mh = 0; mh < 2; ++mh) {
      pa[mh][0] = ld_frag16(&Ps[w][(mh * 16 + l16) * 72 + ((quad ^ rsw) << 3)]);
      pa[mh][1] = ld_frag16(&Ps[w][(mh * 16 + l16) * 72 + (((4 + quad) ^ rsw) << 3)]);
    }
#pragma unroll
    for (int nt = 0; nt < 4; ++nt) {
      const int dh = nt * 16 + l16;
      const int sdh = (dh >> 3) & 7;
      bf16x8 vf0 = ld_frag16(&Vt[dh * 72 + ((quad ^ sdh) << 3)]);
      bf16x8 vf1 = ld_frag16(&Vt[dh * 72 + (((4 + quad) ^ sdh) << 3)]);
#pragma unroll
      for (int mh = 0; mh < 2; ++mh) {
        accO[mh][nt] = __builtin_amdgcn_mfma_f32_16x16x32_bf16(pa[mh][0], vf0, accO[mh][nt], 0, 0, 0);
        accO[mh][nt] = __builtin_amdgcn_mfma_f32_16x16x32_bf16(pa[mh][1], vf1, accO[mh][nt], 0, 0, 0);
      }
    }
#pragma unroll
    for (int mh = 0; mh < 2; ++mh) {
      accl[mh] = __builtin_amdgcn_mfma_f32_16x16x32_bf16(pa[mh][0], ones, accl[mh], 0, 0, 0);
      accl[mh] = __builtin_amdgcn_mfma_f32_16x16x32_bf16(pa[mh][1], ones, accl[mh], 0, 0, 0);
    }
  }

#pragma unroll
  for (int mh = 0; mh < 2; ++mh)
#pragma unroll
    for (int nt = 0; nt < 4; ++nt)
#pragma unroll
      for (int reg = 0; reg < 4; ++reg) {
        const int r = s0 + w * 32 + mh * 16 + quad * 4 + reg;
        const int c = h * DHD + nt * 16 + l16;
        O[(size_t)(b * SS + r) * DD + c] = (bf16_t)(accO[mh][nt][reg] / accl[mh][reg]);
      }
}

// ---------------------------------------------------------------------------
// y = LayerNorm(x + a) * g + b.  One block per row.  Alias-safe (Y==X ok).
// ---------------------------------------------------------------------------
__global__ __launch_bounds__(256) void ln_add_k(const bf16_t* __restrict__ X,
                                                const bf16_t* __restrict__ A,
                                                const void* __restrict__ g,
                                                const void* __restrict__ bb,
                                                void* __restrict__ Yv,
                                                const int* __restrict__ flg,
                                                int final_out) {
  const int row = blockIdx.x;
  const int t = threadIdx.x;
  const int f32m = flg[0];
  const int f32o = final_out ? f32m : 0;
  const bf16_t* xp = X + (size_t)row * DD;
  const bf16_t* ap = A + (size_t)row * DD;
  U4v xu, au;
  xu.u = ((const uint2*)xp)[t];
  au.u = ((const uint2*)ap)[t];
  float v[4], s = 0.f, sq = 0.f;
#pragma unroll
  for (int i = 0; i < 4; ++i) {
    float xv = (float)xu.e[i] + (float)au.e[i];
    v[i] = xv; s += xv; sq += xv * xv;
  }
#pragma unroll
  for (int off = 1; off < 64; off <<= 1) {
    s  += __shfl_xor(s, off, 64);
    sq += __shfl_xor(sq, off, 64);
  }
  __shared__ float red[2][4];
  const int w = t >> 6, lane = t & 63;
  if (lane == 0) { red[0][w] = s; red[1][w] = sq; }
  __syncthreads();
  s  = red[0][0] + red[0][1] + red[0][2] + red[0][3];
  sq = red[1][0] + red[1][1] + red[1][2] + red[1][3];
  const float mean = s * (1.f / 1024.f);
  const float var  = sq * (1.f / 1024.f) - mean * mean;
  const float rstd = rsqrtf(var + 1e-5f);
  float gv[4], bv[4];
  if (f32m) {
    float4 gg = ((const float4*)g)[t];
    float4 bg = ((const float4*)bb)[t];
    gv[0]=gg.x; gv[1]=gg.y; gv[2]=gg.z; gv[3]=gg.w;
    bv[0]=bg.x; bv[1]=bg.y; bv[2]=bg.z; bv[3]=bg.w;
  } else {
    U4v gg, bg;
    gg.u = ((const uint2*)g)[t];
    bg.u = ((const uint2*)bb)[t];
#pragma unroll
    for (int i = 0; i < 4; ++i) { gv[i] = (float)gg.e[i]; bv[i] = (float)bg.e[i]; }
  }
  float val[4];
#pragma unroll
  for (int i = 0; i < 4; ++i) val[i] = (v[i] - mean) * rstd * gv[i] + bv[i];
  if (f32o) {
    float4 o; o.x = val[0]; o.y = val[1]; o.z = val[2]; o.w = val[3];
    ((float4*)((float*)Yv + (size_t)row * DD))[t] = o;
  } else {
    U4v o;
#pragma unroll
    for (int i = 0; i < 4; ++i) o.e[i] = (bf16_t)val[i];
    ((uint2*)((bf16_t*)Yv + (size_t)row * DD))[t] = o.u;
  }
}

// ---------------------------------------------------------------------------
__global__ __launch_bounds__(256) void beacon_k(bf16_t* out, int n, float val) {
  int i = blockIdx.x * 256 + threadIdx.x;
  if (i < n) out[i] = (bf16_t)val;
}

// ---------------------------------------------------------------------------
extern "C" void kernel_launch(void* const* d_in, const int* in_sizes, int n_in,
                              void* d_out, int out_size, void* d_ws, size_t ws_size,
                              hipStream_t stream) {
  const dim3 blk(256);
  const dim3 gB((out_size + 255) / 256);

  static const int expect[24] = {
    4194304, 4194304,
    1048576, 1048576, 1048576, 1048576, 1024,
    1048576, 1048576, 1048576, 1048576, 1024,
    1024, 1024, 1024, 1024, 1024, 1024,
    4194304, 4096,
    4194304, 1024,
    4096, 4096
  };
  if (n_in != 24) {
    beacon_k<<<gB, blk, 0, stream>>>((bf16_t*)d_out, out_size, 200.f + (float)(n_in & 63));
    return;
  }
  for (int i = 0; i < 24; ++i) {
    if (in_sizes[i] != expect[i]) {
      beacon_k<<<gB, blk, 0, stream>>>((bf16_t*)d_out, out_size, 20.f + 2.f * (float)i);
      return;
    }
  }

  const void* x_raw   = d_in[0];
  const void* enc_raw = d_in[1];
  const void* sa_wq = d_in[2], *sa_wk = d_in[3], *sa_wv = d_in[4], *sa_wo = d_in[5];
  const void* sa_bo = d_in[6];
  const void* ca_wq = d_in[7], *ca_wk = d_in[8], *ca_wv = d_in[9], *ca_wo = d_in[10];
  const void* ca_bo = d_in[11];
  const void* ln1_g = d_in[12], *ln1_b = d_in[13];
  const void* ln2_g = d_in[14], *ln2_b = d_in[15];
  const void* ln3_g = d_in[16], *ln3_b = d_in[17];
  const void* fc1_w = d_in[18], *fc1_b = d_in[19];
  const void* fc2_w = d_in[20], *fc2_b = d_in[21];
  const int* tgt_mask = (const int*)d_in[22];
  const int* src_mask = (const int*)d_in[23];

  const size_t SEG = (size_t)NROWS * DD;           // 4,194,304 elems = 8 MiB bf16
  const size_t PS_ELEMS = 32768;
  if (ws_size < (8 * SEG + PS_ELEMS) * sizeof(bf16_t)) {
    beacon_k<<<gB, blk, 0, stream>>>((bf16_t*)d_out, out_size, 7.f);
    return;
  }
  bf16_t* ws  = (bf16_t*)d_ws;
  bf16_t* qkv = ws + 0 * SEG;       // seg0-2: interleaved [4096][3072] Q|K|V
  bf16_t* wt  = ws + 3 * SEG;       // seg3: 4 transposed DxD weights / fc1^T / fc2^T
  bf16_t* t1  = ws + 4 * SEG;       // attn-proj out / ff out
  bf16_t* x1  = ws + 5 * SEG;       // ln1 out; ln2 in-place out; self-attn t0
  bf16_t* xc  = ws + 6 * SEG;       // canonical bf16 x; cross-attn t0 after ln1
  bf16_t* ec  = ws + 7 * SEG;       // canonical bf16 enc
  bf16_t* ps  = ws + 8 * SEG;
  int*    fl  = (int*)(ps + 16384); // flags
  const bool big_ws = ws_size >= (12 * SEG + PS_ELEMS) * sizeof(bf16_t);
  bf16_t* hb = ws + 8 * SEG + PS_ELEMS;

  const size_t W1 = (size_t)DD * DD;   // 1M elems per transposed DxD weight
  bf16_t* wot = wt + 3 * W1;

  const dim3 gT4(16, 16, 4);
  const dim3 gP(DD / 128, NROWS / 64);         // proj/fc2: 512 blocks = 2/CU
  const dim3 gQKV(3 * DD / 128, NROWS / 64);   // QKV fused: 1536 blocks = 6/CU
  const dim3 gFC1(FFD / 128, NROWS / 64);      // fc1: 2048 blocks = 8/CU
  const dim3 gA(SS / 128, BB * HH);            // attn QBLK=128: 512 blocks
  const dim3 gL(NROWS);
  const dim3 gC(512);

  // ---- detect dtypes, canonicalize activations ----
  detect_k<<<dim3(1), blk, 0, stream>>>(x_raw, enc_raw, fc1_w, tgt_mask, fl);
  cvt_k<<<gC, blk, 0, stream>>>(x_raw,   xc, (int)SEG, fl);
  cvt_k<<<gC, blk, 0, stream>>>(enc_raw, ec, (int)SEG, fl);

  // ---- self attention ----
  { Ptr4 p{sa_wq, sa_wk, sa_wv, sa_wo};
    transpose4_k<<<gT4, blk, 0, stream>>>(p, wt, fl); }
  gemm64<0,0><<<gQKV, blk, 0, stream>>>(xc, nullptr, 0, wt, nullptr, qkv,
                                        NROWS, 3 * DD, DD, QLD, fl);
  attn_k<<<gA, blk, 0, stream>>>(qkv, tgt_mask, x1, fl);
  gemm64<1,0><<<gP, blk, 0, stream>>>(x1, nullptr, 0, wot, sa_bo, t1,
                                      NROWS, DD, DD, DD, fl);
  ln_add_k<<<gL, blk, 0, stream>>>(xc, t1, ln1_g, ln1_b, x1, fl, 0);

  // ---- cross attention (Q from x1, K/V from ec: fused via per-block A split) ----
  { Ptr4 p{ca_wq, ca_wk, ca_wv, ca_wo};
    transpose4_k<<<gT4, blk, 0, stream>>>(p, wt, fl); }
  gemm64<0,0><<<gQKV, blk, 0, stream>>>(x1, ec, DD, wt, nullptr, qkv,
                                        NROWS, 3 * DD, DD, QLD, fl);
  attn_k<<<gA, blk, 0, stream>>>(qkv, src_mask, xc, fl);
  gemm64<1,0><<<gP, blk, 0, stream>>>(xc, nullptr, 0, wot, ca_bo, t1,
                                      NROWS, DD, DD, DD, fl);
  ln_add_k<<<gL, blk, 0, stream>>>(x1, t1, ln2_g, ln2_b, x1, fl, 0);

  // ---- MLP (x2 == x1) ----
  transpose_k<<<dim3(FFD/64, DD/64), blk, 0, stream>>>(fc1_w, wt, DD, FFD, fl);  // fc1^T
  if (big_ws) {
    gemm64<1,1><<<gFC1, blk, 0, stream>>>(x1, nullptr, 0, wt, fc1_b, hb,
                                          NROWS, FFD, DD, FFD, fl);
    transpose_k<<<dim3(DD/64, FFD/64), blk, 0, stream>>>(fc2_w, wt, FFD, DD, fl); // fc2^T
    gemm64<1,0><<<gP, blk, 0, stream>>>(hb, nullptr, 0, wt, fc2_b, t1,
                                        NROWS, DD, FFD, DD, fl);
  } else {
    // qkv segs are free now: seg0 = fc2^T, seg1 = h-chunk [1024][4096]
    transpose_k<<<dim3(DD/64, FFD/64), blk, 0, stream>>>(fc2_w, qkv, FFD, DD, fl); // fc2^T
    bf16_t* hchunk = qkv + SEG;
    for (int c = 0; c < 4; ++c) {
      gemm64<1,1><<<dim3(FFD/128, 16), blk, 0, stream>>>(x1 + (size_t)c*1024*DD, nullptr, 0, wt,
                                                         fc1_b, hchunk, 1024, FFD, DD, FFD, fl);
      gemm64<1,0><<<dim3(DD/128, 16), blk, 0, stream>>>(hchunk, nullptr, 0, qkv, fc2_b,
                                                        t1 + (size_t)c*1024*DD, 1024, DD, FFD, DD, fl);
    }
  }
  ln_add_k<<<gL, blk, 0, stream>>>(x1, t1, ln3_g, ln3_b, d_out, fl, 1);
}

// Round 9
// 634.131 us; speedup vs baseline: 1.0385x; 1.0385x over previous
//
#include <hip/hip_runtime.h>
#include <hip/hip_bf16.h>
#include <math.h>

// Problem constants (B=2, S=2048, D=1024, H=16, DH=64, FF=4096)
#define BB 2
#define SS 2048
#define DD 1024
#define HH 16
#define DHD 64
#define FFD 4096
#define NROWS (BB*SS)
#define QLD 3072   // interleaved QKV row stride

typedef __bf16 bf16_t;
typedef __bf16 bf16x8 __attribute__((ext_vector_type(8)));
typedef float floatx4 __attribute__((ext_vector_type(4)));

union FragU { uint4 u; bf16x8 v; bf16_t e[8]; };
union U4v  { uint2 u; bf16_t e[4]; };

static __device__ __forceinline__ bf16x8 ld_frag16(const bf16_t* p) {
  FragU f; f.u = *reinterpret_cast<const uint4*>(p); return f.v;
}

// async global->LDS 16B: lane i of the wave lands at lptr + i*16 (wave-uniform base!)
static __device__ __forceinline__ void gl_lds16(const bf16_t* g, bf16_t* l) {
  __builtin_amdgcn_global_load_lds(
      (const __attribute__((address_space(1))) unsigned int*)g,
      (__attribute__((address_space(3))) unsigned int*)l, 16, 0, 0);
}

// flag-dependent scalar read of a "float param" tensor (f32 or bf16)
static __device__ __forceinline__ float ld_param(const void* p, int i, int f32m) {
  return f32m ? ((const float*)p)[i] : (float)((const bf16_t*)p)[i];
}

// ---------------------------------------------------------------------------
// Detector: flags[0]=1 if float tensors are really f32; flags[1]=1 if masks int8.
// ---------------------------------------------------------------------------
__global__ __launch_bounds__(256) void detect_k(const void* __restrict__ xp,
                                                const void* __restrict__ ep,
                                                const void* __restrict__ wp,
                                                const int* __restrict__ mk,
                                                int* __restrict__ flags) {
  const int t = threadIdx.x;
  const unsigned short* a = (const unsigned short*)xp;
  const unsigned short* b = (const unsigned short*)ep;
  const unsigned short* c = (const unsigned short*)wp;
  int bad = 0, mbad = 0;
  for (int i = t; i < 4096; i += 256) {
    int e1 = (a[i] >> 7) & 0xFF, e2 = (b[i] >> 7) & 0xFF, e3 = (c[i] >> 7) & 0xFF;
    if (e1 >= 0x9B || e2 >= 0x9B || e3 >= 0x9B) bad = 1;
  }
  for (int i = t; i < 1024; i += 256) {
    unsigned v = (unsigned)mk[i];
    if (v > 1u) mbad = 1;
  }
  __shared__ int s0, s1;
  if (t == 0) { s0 = 0; s1 = 0; }
  __syncthreads();
  if (bad)  atomicOr(&s0, 1);
  if (mbad) atomicOr(&s1, 1);
  __syncthreads();
  if (t == 0) { flags[0] = s0; flags[1] = s1; }
}

// ---------------------------------------------------------------------------
// Canonicalize a float tensor to bf16 (copy if already bf16). Vectorized 8/thread.
// ---------------------------------------------------------------------------
__global__ __launch_bounds__(256) void cvt_k(const void* __restrict__ src,
                                             bf16_t* __restrict__ dst, int n,
                                             const int* __restrict__ flg) {
  const int f32m = flg[0];
  const int idx = blockIdx.x * 256 + threadIdx.x;
  const int stride = gridDim.x * 256;
  const int n8 = n >> 3;
  if (f32m) {
    const float4* s = (const float4*)src;
    for (int i = idx; i < n8; i += stride) {
      float4 a = s[2 * i], b = s[2 * i + 1];
      FragU f;
      f.e[0] = (bf16_t)a.x; f.e[1] = (bf16_t)a.y; f.e[2] = (bf16_t)a.z; f.e[3] = (bf16_t)a.w;
      f.e[4] = (bf16_t)b.x; f.e[5] = (bf16_t)b.y; f.e[6] = (bf16_t)b.z; f.e[7] = (bf16_t)b.w;
      *reinterpret_cast<uint4*>(dst + (size_t)i * 8) = f.u;
    }
  } else {
    const uint4* s = (const uint4*)src;
    uint4* d = (uint4*)dst;
    for (int i = idx; i < n8; i += stride) d[i] = s[i];
  }
}

// ---------------------------------------------------------------------------
// Transpose core (shared by single & batched kernels).
// ---------------------------------------------------------------------------
static __device__ __forceinline__ void transpose_body(const void* inv, bf16_t* out,
                                                      int rows, int cols, int f32m) {
  __shared__ __align__(16) bf16_t tile[64][72];
  const int c0 = blockIdx.x * 64, r0 = blockIdx.y * 64;
  const int t  = threadIdx.x;
  const int lr = t >> 3;            // 0..31
  const int lc = (t & 7) * 8;       // 0..56
#pragma unroll
  for (int half = 0; half < 2; ++half) {
    int r = lr + half * 32;
    if (f32m) {
      const float* p = (const float*)inv + (size_t)(r0 + r) * cols + c0 + lc;
      float4 q0 = *reinterpret_cast<const float4*>(p);
      float4 q1 = *reinterpret_cast<const float4*>(p + 4);
      tile[r][lc+0] = (bf16_t)q0.x; tile[r][lc+1] = (bf16_t)q0.y;
      tile[r][lc+2] = (bf16_t)q0.z; tile[r][lc+3] = (bf16_t)q0.w;
      tile[r][lc+4] = (bf16_t)q1.x; tile[r][lc+5] = (bf16_t)q1.y;
      tile[r][lc+6] = (bf16_t)q1.z; tile[r][lc+7] = (bf16_t)q1.w;
    } else {
      uint4 vv = *reinterpret_cast<const uint4*>((const bf16_t*)inv + (size_t)(r0 + r) * cols + c0 + lc);
      *reinterpret_cast<uint4*>(&tile[r][lc]) = vv;
    }
  }
  __syncthreads();
#pragma unroll
  for (int half = 0; half < 2; ++half) {
    int oc = lr + half * 32;
    FragU f;
#pragma unroll
    for (int j = 0; j < 8; ++j) f.e[j] = tile[lc + j][oc];
    *reinterpret_cast<uint4*>(out + (size_t)(c0 + oc) * rows + r0 + lc) = f.u;
  }
}

__global__ __launch_bounds__(256) void transpose_k(const void* __restrict__ inv,
                                                   bf16_t* __restrict__ out,
                                                   int rows, int cols,
                                                   const int* __restrict__ flg) {
  transpose_body(inv, out, rows, cols, flg[0]);
}

struct Ptr4 { const void* p0; const void* p1; const void* p2; const void* p3; };

// 4 D x D transposes in one launch: grid (16,16,4)
__global__ __launch_bounds__(256) void transpose4_k(Ptr4 in, bf16_t* __restrict__ out,
                                                    const int* __restrict__ flg) {
  const void* src = (blockIdx.z == 0) ? in.p0 : (blockIdx.z == 1) ? in.p1
                   : (blockIdx.z == 2) ? in.p2 : in.p3;
  transpose_body(src, out + (size_t)blockIdx.z * DD * DD, DD, DD, flg[0]);
}

// ---------------------------------------------------------------------------
// gemm_nt (m97-style): 128x128 tile, BK=32, 4 waves. Used for QKV (N=3072,
// 768 blocks = 3/CU, high compute-intensity — r6 ran it <102 µs).
// A2/nsplit: blocks with n0>=nsplit read A2 (cross-attn fusion).
// ---------------------------------------------------------------------------
template<int BIAS, int GELU>
__global__ __launch_bounds__(256) void gemm_nt(const bf16_t* __restrict__ A,
                                               const bf16_t* __restrict__ A2,
                                               int nsplit,
                                               const bf16_t* __restrict__ Bt,
                                               const void* __restrict__ bias,
                                               bf16_t* __restrict__ C,
                                               int M, int N, int K, int ldc,
                                               const int* __restrict__ flg) {
  __shared__ __align__(16) bf16_t As[128 * 32];
  __shared__ __align__(16) bf16_t Bs[128 * 32];
  const int m0 = blockIdx.y * 128, n0 = blockIdx.x * 128;
  const bf16_t* Ap = (A2 != nullptr && n0 >= nsplit) ? A2 : A;
  const int t = threadIdx.x, lane = t & 63, w = t >> 6;
  const int quad = lane >> 4, l16 = lane & 15;
  const int wy = w >> 1, wx = w & 1;

  floatx4 acc[4][4];
#pragma unroll
  for (int i = 0; i < 4; ++i)
#pragma unroll
    for (int j = 0; j < 4; ++j) { floatx4 z = {0.f,0.f,0.f,0.f}; acc[i][j] = z; }

  const int srow = lane >> 2;
  const int scol = (lane & 3) * 8;

  for (int k0 = 0; k0 < K; k0 += 32) {
    __syncthreads();
#pragma unroll
    for (int c = 0; c < 2; ++c) {
      const int chunk = w * 2 + c;
      const int r = chunk * 16 + srow;
      gl_lds16(Ap + (size_t)(m0 + r) * K + k0 + scol, As + chunk * 512);
      gl_lds16(Bt + (size_t)(n0 + r) * K + k0 + scol, Bs + chunk * 512);
    }
    __syncthreads();

    bf16x8 af[4], bfr[4];
#pragma unroll
    for (int mt = 0; mt < 4; ++mt) af[mt]  = ld_frag16(As + (wy*64 + mt*16 + l16) * 32 + quad*8);
#pragma unroll
    for (int nt = 0; nt < 4; ++nt) bfr[nt] = ld_frag16(Bs + (wx*64 + nt*16 + l16) * 32 + quad*8);
#pragma unroll
    for (int mt = 0; mt < 4; ++mt)
#pragma unroll
      for (int nt = 0; nt < 4; ++nt)
        acc[mt][nt] = __builtin_amdgcn_mfma_f32_16x16x32_bf16(af[mt], bfr[nt], acc[mt][nt], 0, 0, 0);
  }

  const int f32m = BIAS ? flg[0] : 0;
#pragma unroll
  for (int nt = 0; nt < 4; ++nt) {
    const int c = n0 + wx*64 + nt*16 + l16;
    float bv = 0.f;
    if (BIAS) bv = ld_param(bias, c, f32m);
#pragma unroll
    for (int mt = 0; mt < 4; ++mt) {
      const int rb = m0 + wy*64 + mt*16 + quad*4;
#pragma unroll
      for (int reg = 0; reg < 4; ++reg) {
        float v2 = acc[mt][nt][reg] + bv;
        if (GELU) v2 = 0.5f * v2 * (1.f + erff(v2 * 0.70710678118654752f));
        C[(size_t)(rb + reg) * ldc + c] = (bf16_t)v2;
      }
    }
  }
}

// ---------------------------------------------------------------------------
// gemm64: 64x128 tile. Used for proj/fc2 (N=1024: 512 blocks = 2/CU, r6 win)
// and fc1 (N=4096: 2048 blocks = 8/CU, r8 showed <92.5 µs vs r7's 143).
// ---------------------------------------------------------------------------
template<int BIAS, int GELU>
__global__ __launch_bounds__(256) void gemm64(const bf16_t* __restrict__ A,
                                              const bf16_t* __restrict__ A2,
                                              int nsplit,
                                              const bf16_t* __restrict__ Bt,
                                              const void* __restrict__ bias,
                                              bf16_t* __restrict__ C,
                                              int M, int N, int K, int ldc,
                                              const int* __restrict__ flg) {
  __shared__ __align__(16) bf16_t As[64 * 32];
  __shared__ __align__(16) bf16_t Bs[128 * 32];
  const int m0 = blockIdx.y * 64, n0 = blockIdx.x * 128;
  const bf16_t* Ap = (A2 != nullptr && n0 >= nsplit) ? A2 : A;
  const int t = threadIdx.x, lane = t & 63, w = t >> 6;
  const int quad = lane >> 4, l16 = lane & 15;
  const int wy = w >> 1, wx = w & 1;

  floatx4 acc[2][4];
#pragma unroll
  for (int i = 0; i < 2; ++i)
#pragma unroll
    for (int j = 0; j < 4; ++j) { floatx4 z = {0.f,0.f,0.f,0.f}; acc[i][j] = z; }

  const int srow = lane >> 2;
  const int scol = (lane & 3) * 8;

  for (int k0 = 0; k0 < K; k0 += 32) {
    __syncthreads();
    gl_lds16(Ap + (size_t)(m0 + w * 16 + srow) * K + k0 + scol, As + w * 512);
#pragma unroll
    for (int c = 0; c < 2; ++c) {
      const int chunk = w * 2 + c;
      gl_lds16(Bt + (size_t)(n0 + chunk * 16 + srow) * K + k0 + scol, Bs + chunk * 512);
    }
    __syncthreads();

    bf16x8 af[2], bfr[4];
#pragma unroll
    for (int mt = 0; mt < 2; ++mt) af[mt]  = ld_frag16(As + (wy*32 + mt*16 + l16) * 32 + quad*8);
#pragma unroll
    for (int nt = 0; nt < 4; ++nt) bfr[nt] = ld_frag16(Bs + (wx*64 + nt*16 + l16) * 32 + quad*8);
#pragma unroll
    for (int mt = 0; mt < 2; ++mt)
#pragma unroll
      for (int nt = 0; nt < 4; ++nt)
        acc[mt][nt] = __builtin_amdgcn_mfma_f32_16x16x32_bf16(af[mt], bfr[nt], acc[mt][nt], 0, 0, 0);
  }

  const int f32m = BIAS ? flg[0] : 0;
#pragma unroll
  for (int nt = 0; nt < 4; ++nt) {
    const int c = n0 + wx*64 + nt*16 + l16;
    float bv = 0.f;
    if (BIAS) bv = ld_param(bias, c, f32m);
#pragma unroll
    for (int mt = 0; mt < 2; ++mt) {
      const int rb = m0 + wy*32 + mt*16 + quad*4;
#pragma unroll
      for (int reg = 0; reg < 4; ++reg) {
        float v2 = acc[mt][nt][reg] + bv;
        if (GELU) v2 = 0.5f * v2 * (1.f + erff(v2 * 0.70710678118654752f));
        C[(size_t)(rb + reg) * ldc + c] = (bf16_t)v2;
      }
    }
  }
}

// ---------------------------------------------------------------------------
// MFMA flash attention, 64-key tiles, QBLK=128.
// QKV interleaved [B*S, 3072] (Q|K|V). grid (S/128, B*H) = 512 blocks = 2/CU.
// 4 waves x 32 q-rows (two 16-row groups mh=0,1): each K/V fragment read from
// LDS feeds TWO MFMAs. Static-max softmax (-8), Ps chunk-swizzled.
// ---------------------------------------------------------------------------
__global__ __launch_bounds__(256, 2) void attn_k(const bf16_t* __restrict__ QKV,
                                                 const int* __restrict__ mask,
                                                 bf16_t* __restrict__ O,
                                                 const int* __restrict__ flg) {
  __shared__ __align__(16) bf16_t Ks[64 * 72];    // [key][dh] stride 72
  __shared__ __align__(16) bf16_t Vt[64 * 72];    // [dh][key, chunk-swizzled]
  __shared__ __align__(16) bf16_t Ps[4][32 * 72]; // per-wave P [qrow][key], chunk-swizzled
  __shared__ bf16_t msk[SS];                      // additive mask row (-8 / -1e30)
  const int mflag = flg[1];
  const int b = blockIdx.y >> 4, h = blockIdx.y & 15;
  const int s0 = blockIdx.x * 128;
  const int t = threadIdx.x, w = t >> 6, lane = t & 63;
  const int quad = lane >> 4, l16 = lane & 15;
  const float L2S = 0.18033688011112042f;   // 0.125 * log2(e)

  for (int j = t; j < SS; j += 256) {
    const int mv = mflag ? (int)((const signed char*)mask)[b * SS + j] : mask[b * SS + j];
    msk[j] = (bf16_t)(mv ? -1.0e30f : -8.0f);
  }

  // Q A-fragments for both 16-row groups
  bf16x8 qf[2][2];
#pragma unroll
  for (int mh = 0; mh < 2; ++mh) {
    const int r = s0 + w * 32 + mh * 16 + l16;
    const bf16_t* qp = QKV + (size_t)(b * SS + r) * QLD + h * DHD;
#pragma unroll
    for (int kq = 0; kq < 2; ++kq) qf[mh][kq] = ld_frag16(qp + kq * 32 + quad * 8);
  }

  bf16x8 ones;
#pragma unroll
  for (int j = 0; j < 8; ++j) ones[j] = (bf16_t)1.0f;

  floatx4 accO[2][4], accl[2];
  { floatx4 z = {0.f,0.f,0.f,0.f};
#pragma unroll
    for (int mh = 0; mh < 2; ++mh) { accl[mh] = z;
#pragma unroll
      for (int i = 0; i < 4; ++i) accO[mh][i] = z; } }

  const int krow = t >> 2, kc = (t & 3) * 16;
  const int vkey = t & 63, vw16 = (t >> 6) * 16;
  const int vq = vkey >> 3, vk7 = vkey & 7;
  const int vs0 = (vw16 >> 3) & 7, vs1 = (vs0 + 1) & 7;

  int coff[4];
#pragma unroll
  for (int cf = 0; cf < 4; ++cf)
    coff[cf] = (((((cf << 1) | (l16 >> 3))) ^ ((quad >> 1) << 1)) << 3) + (l16 & 7);
  const int rsw = ((l16 >> 3) & 1) << 1;

  const bf16_t* kp = QKV + 1024 + (size_t)(b * SS + krow) * QLD + h * DHD + kc;
  const bf16_t* vp = QKV + 2048 + (size_t)(b * SS + vkey) * QLD + h * DHD + vw16;

  uint4 kr0 = *reinterpret_cast<const uint4*>(kp);
  uint4 kr1 = *reinterpret_cast<const uint4*>(kp + 8);
  uint4 vr0 = *reinterpret_cast<const uint4*>(vp);
  uint4 vr1 = *reinterpret_cast<const uint4*>(vp + 8);

  for (int j0 = 0; j0 < SS; j0 += 64) {
    __syncthreads();
    *reinterpret_cast<uint4*>(&Ks[krow * 72 + kc])     = kr0;
    *reinterpret_cast<uint4*>(&Ks[krow * 72 + kc + 8]) = kr1;
    { FragU v0; v0.u = vr0; FragU v1; v1.u = vr1;
#pragma unroll
      for (int j = 0; j < 8; ++j) Vt[(vw16 + j) * 72 + ((vq ^ vs0) << 3) + vk7] = v0.e[j];
#pragma unroll
      for (int j = 0; j < 8; ++j) Vt[(vw16 + 8 + j) * 72 + ((vq ^ vs1) << 3) + vk7] = v1.e[j];
    }
    __syncthreads();

    if (j0 + 64 < SS) {
      const bf16_t* kp2 = kp + (size_t)(j0 + 64) * QLD;
      const bf16_t* vp2 = vp + (size_t)(j0 + 64) * QLD;
      kr0 = *reinterpret_cast<const uint4*>(kp2);
      kr1 = *reinterpret_cast<const uint4*>(kp2 + 8);
      vr0 = *reinterpret_cast<const uint4*>(vp2);
      vr1 = *reinterpret_cast<const uint4*>(vp2 + 8);
    }

    // S = Q K^T : each Ks fragment feeds both mh groups
    floatx4 s4[2][4];
    { floatx4 z = {0.f,0.f,0.f,0.f};
#pragma unroll
      for (int mh = 0; mh < 2; ++mh)
#pragma unroll
        for (int cf = 0; cf < 4; ++cf) s4[mh][cf] = z; }
#pragma unroll
    for (int kq = 0; kq < 2; ++kq)
#pragma unroll
      for (int cf = 0; cf < 4; ++cf) {
        bf16x8 bf = ld_frag16(&Ks[(cf * 16 + l16) * 72 + kq * 32 + quad * 8]);
#pragma unroll
        for (int mh = 0; mh < 2; ++mh)
          s4[mh][cf] = __builtin_amdgcn_mfma_f32_16x16x32_bf16(qf[mh][kq], bf, s4[mh][cf], 0, 0, 0);
      }
    float ml[4];
#pragma unroll
    for (int cf = 0; cf < 4; ++cf) ml[cf] = (float)msk[j0 + cf * 16 + l16];

    // static-max softmax for both groups
#pragma unroll
    for (int mh = 0; mh < 2; ++mh)
#pragma unroll
      for (int reg = 0; reg < 4; ++reg) {
        const float p0 = exp2f(fmaf(s4[mh][0][reg], L2S, ml[0]));
        const float p1 = exp2f(fmaf(s4[mh][1][reg], L2S, ml[1]));
        const float p2 = exp2f(fmaf(s4[mh][2][reg], L2S, ml[2]));
        const float p3 = exp2f(fmaf(s4[mh][3][reg], L2S, ml[3]));
        const int rb = (mh * 16 + quad * 4 + reg) * 72;
        Ps[w][rb + coff[0]] = (bf16_t)p0;
        Ps[w][rb + coff[1]] = (bf16_t)p1;
        Ps[w][rb + coff[2]] = (bf16_t)p2;
        Ps[w][rb + coff[3]] = (bf16_t)p3;
      }
    asm volatile("s_waitcnt lgkmcnt(0)" ::: "memory");

    // O += P V ; l += P 1 : each Vt fragment feeds both mh groups
    bf16x8 pa[2][2];
#pragma unroll
    for (int mh = 0; mh < 2; ++mh) {
      pa[mh][0] = ld_frag16(&Ps[w][(mh * 16 + l16) * 72 + ((quad ^ rsw) << 3)]);
      pa[mh][1] = ld_frag16(&Ps[w][(mh * 16 + l16) * 72 + (((4 + quad) ^ rsw) << 3)]);
    }
#pragma unroll
    for (int nt = 0; nt < 4; ++nt) {
      const int dh = nt * 16 + l16;
      const int sdh = (dh >> 3) & 7;
      bf16x8 vf0 = ld_frag16(&Vt[dh * 72 + ((quad ^ sdh) << 3)]);
      bf16x8 vf1 = ld_frag16(&Vt[dh * 72 + (((4 + quad) ^ sdh) << 3)]);
#pragma unroll
      for (int mh = 0; mh < 2; ++mh) {
        accO[mh][nt] = __builtin_amdgcn_mfma_f32_16x16x32_bf16(pa[mh][0], vf0, accO[mh][nt], 0, 0, 0);
        accO[mh][nt] = __builtin_amdgcn_mfma_f32_16x16x32_bf16(pa[mh][1], vf1, accO[mh][nt], 0, 0, 0);
      }
    }
#pragma unroll
    for (int mh = 0; mh < 2; ++mh) {
      accl[mh] = __builtin_amdgcn_mfma_f32_16x16x32_bf16(pa[mh][0], ones, accl[mh], 0, 0, 0);
      accl[mh] = __builtin_amdgcn_mfma_f32_16x16x32_bf16(pa[mh][1], ones, accl[mh], 0, 0, 0);
    }
  }

#pragma unroll
  for (int mh = 0; mh < 2; ++mh)
#pragma unroll
    for (int nt = 0; nt < 4; ++nt)
#pragma unroll
      for (int reg = 0; reg < 4; ++reg) {
        const int r = s0 + w * 32 + mh * 16 + quad * 4 + reg;
        const int c = h * DHD + nt * 16 + l16;
        O[(size_t)(b * SS + r) * DD + c] = (bf16_t)(accO[mh][nt][reg] / accl[mh][reg]);
      }
}

// ---------------------------------------------------------------------------
// y = LayerNorm(x + a) * g + b.  One block per row.  Alias-safe (Y==X ok).
// ---------------------------------------------------------------------------
__global__ __launch_bounds__(256) void ln_add_k(const bf16_t* __restrict__ X,
                                                const bf16_t* __restrict__ A,
                                                const void* __restrict__ g,
                                                const void* __restrict__ bb,
                                                void* __restrict__ Yv,
                                                const int* __restrict__ flg,
                                                int final_out) {
  const int row = blockIdx.x;
  const int t = threadIdx.x;
  const int f32m = flg[0];
  const int f32o = final_out ? f32m : 0;
  const bf16_t* xp = X + (size_t)row * DD;
  const bf16_t* ap = A + (size_t)row * DD;
  U4v xu, au;
  xu.u = ((const uint2*)xp)[t];
  au.u = ((const uint2*)ap)[t];
  float v[4], s = 0.f, sq = 0.f;
#pragma unroll
  for (int i = 0; i < 4; ++i) {
    float xv = (float)xu.e[i] + (float)au.e[i];
    v[i] = xv; s += xv; sq += xv * xv;
  }
#pragma unroll
  for (int off = 1; off < 64; off <<= 1) {
    s  += __shfl_xor(s, off, 64);
    sq += __shfl_xor(sq, off, 64);
  }
  __shared__ float red[2][4];
  const int w = t >> 6, lane = t & 63;
  if (lane == 0) { red[0][w] = s; red[1][w] = sq; }
  __syncthreads();
  s  = red[0][0] + red[0][1] + red[0][2] + red[0][3];
  sq = red[1][0] + red[1][1] + red[1][2] + red[1][3];
  const float mean = s * (1.f / 1024.f);
  const float var  = sq * (1.f / 1024.f) - mean * mean;
  const float rstd = rsqrtf(var + 1e-5f);
  float gv[4], bv[4];
  if (f32m) {
    float4 gg = ((const float4*)g)[t];
    float4 bg = ((const float4*)bb)[t];
    gv[0]=gg.x; gv[1]=gg.y; gv[2]=gg.z; gv[3]=gg.w;
    bv[0]=bg.x; bv[1]=bg.y; bv[2]=bg.z; bv[3]=bg.w;
  } else {
    U4v gg, bg;
    gg.u = ((const uint2*)g)[t];
    bg.u = ((const uint2*)bb)[t];
#pragma unroll
    for (int i = 0; i < 4; ++i) { gv[i] = (float)gg.e[i]; bv[i] = (float)bg.e[i]; }
  }
  float val[4];
#pragma unroll
  for (int i = 0; i < 4; ++i) val[i] = (v[i] - mean) * rstd * gv[i] + bv[i];
  if (f32o) {
    float4 o; o.x = val[0]; o.y = val[1]; o.z = val[2]; o.w = val[3];
    ((float4*)((float*)Yv + (size_t)row * DD))[t] = o;
  } else {
    U4v o;
#pragma unroll
    for (int i = 0; i < 4; ++i) o.e[i] = (bf16_t)val[i];
    ((uint2*)((bf16_t*)Yv + (size_t)row * DD))[t] = o.u;
  }
}

// ---------------------------------------------------------------------------
__global__ __launch_bounds__(256) void beacon_k(bf16_t* out, int n, float val) {
  int i = blockIdx.x * 256 + threadIdx.x;
  if (i < n) out[i] = (bf16_t)val;
}

// ---------------------------------------------------------------------------
extern "C" void kernel_launch(void* const* d_in, const int* in_sizes, int n_in,
                              void* d_out, int out_size, void* d_ws, size_t ws_size,
                              hipStream_t stream) {
  const dim3 blk(256);
  const dim3 gB((out_size + 255) / 256);

  static const int expect[24] = {
    4194304, 4194304,
    1048576, 1048576, 1048576, 1048576, 1024,
    1048576, 1048576, 1048576, 1048576, 1024,
    1024, 1024, 1024, 1024, 1024, 1024,
    4194304, 4096,
    4194304, 1024,
    4096, 4096
  };
  if (n_in != 24) {
    beacon_k<<<gB, blk, 0, stream>>>((bf16_t*)d_out, out_size, 200.f + (float)(n_in & 63));
    return;
  }
  for (int i = 0; i < 24; ++i) {
    if (in_sizes[i] != expect[i]) {
      beacon_k<<<gB, blk, 0, stream>>>((bf16_t*)d_out, out_size, 20.f + 2.f * (float)i);
      return;
    }
  }

  const void* x_raw   = d_in[0];
  const void* enc_raw = d_in[1];
  const void* sa_wq = d_in[2], *sa_wk = d_in[3], *sa_wv = d_in[4], *sa_wo = d_in[5];
  const void* sa_bo = d_in[6];
  const void* ca_wq = d_in[7], *ca_wk = d_in[8], *ca_wv = d_in[9], *ca_wo = d_in[10];
  const void* ca_bo = d_in[11];
  const void* ln1_g = d_in[12], *ln1_b = d_in[13];
  const void* ln2_g = d_in[14], *ln2_b = d_in[15];
  const void* ln3_g = d_in[16], *ln3_b = d_in[17];
  const void* fc1_w = d_in[18], *fc1_b = d_in[19];
  const void* fc2_w = d_in[20], *fc2_b = d_in[21];
  const int* tgt_mask = (const int*)d_in[22];
  const int* src_mask = (const int*)d_in[23];

  const size_t SEG = (size_t)NROWS * DD;           // 4,194,304 elems = 8 MiB bf16
  const size_t PS_ELEMS = 32768;
  if (ws_size < (8 * SEG + PS_ELEMS) * sizeof(bf16_t)) {
    beacon_k<<<gB, blk, 0, stream>>>((bf16_t*)d_out, out_size, 7.f);
    return;
  }
  bf16_t* ws  = (bf16_t*)d_ws;
  bf16_t* qkv = ws + 0 * SEG;       // seg0-2: interleaved [4096][3072] Q|K|V
  bf16_t* wt  = ws + 3 * SEG;       // seg3: 4 transposed DxD weights / fc1^T / fc2^T
  bf16_t* t1  = ws + 4 * SEG;       // attn-proj out / ff out
  bf16_t* x1  = ws + 5 * SEG;       // ln1 out; ln2 in-place out; self-attn t0
  bf16_t* xc  = ws + 6 * SEG;       // canonical bf16 x; cross-attn t0 after ln1
  bf16_t* ec  = ws + 7 * SEG;       // canonical bf16 enc
  bf16_t* ps  = ws + 8 * SEG;
  int*    fl  = (int*)(ps + 16384); // flags
  const bool big_ws = ws_size >= (12 * SEG + PS_ELEMS) * sizeof(bf16_t);
  bf16_t* hb = ws + 8 * SEG + PS_ELEMS;

  const size_t W1 = (size_t)DD * DD;   // 1M elems per transposed DxD weight
  bf16_t* wot = wt + 3 * W1;

  const dim3 gT4(16, 16, 4);
  const dim3 gP(DD / 128, NROWS / 64);         // proj/fc2: 512 blocks = 2/CU (gemm64)
  const dim3 gQKV(3 * DD / 128, NROWS / 128);  // QKV fused: 768 blocks = 3/CU (gemm_nt)
  const dim3 gFC1(FFD / 128, NROWS / 64);      // fc1: 2048 blocks = 8/CU (gemm64)
  const dim3 gA(SS / 128, BB * HH);            // attn QBLK=128: 512 blocks
  const dim3 gL(NROWS);
  const dim3 gC(512);

  // ---- detect dtypes, canonicalize activations ----
  detect_k<<<dim3(1), blk, 0, stream>>>(x_raw, enc_raw, fc1_w, tgt_mask, fl);
  cvt_k<<<gC, blk, 0, stream>>>(x_raw,   xc, (int)SEG, fl);
  cvt_k<<<gC, blk, 0, stream>>>(enc_raw, ec, (int)SEG, fl);

  // ---- self attention ----
  { Ptr4 p{sa_wq, sa_wk, sa_wv, sa_wo};
    transpose4_k<<<gT4, blk, 0, stream>>>(p, wt, fl); }
  gemm_nt<0,0><<<gQKV, blk, 0, stream>>>(xc, nullptr, 0, wt, nullptr, qkv,
                                         NROWS, 3 * DD, DD, QLD, fl);
  attn_k<<<gA, blk, 0, stream>>>(qkv, tgt_mask, x1, fl);
  gemm64<1,0><<<gP, blk, 0, stream>>>(x1, nullptr, 0, wot, sa_bo, t1,
                                      NROWS, DD, DD, DD, fl);
  ln_add_k<<<gL, blk, 0, stream>>>(xc, t1, ln1_g, ln1_b, x1, fl, 0);

  // ---- cross attention (Q from x1, K/V from ec: fused via per-block A split) ----
  { Ptr4 p{ca_wq, ca_wk, ca_wv, ca_wo};
    transpose4_k<<<gT4, blk, 0, stream>>>(p, wt, fl); }
  gemm_nt<0,0><<<gQKV, blk, 0, stream>>>(x1, ec, DD, wt, nullptr, qkv,
                                         NROWS, 3 * DD, DD, QLD, fl);
  attn_k<<<gA, blk, 0, stream>>>(qkv, src_mask, xc, fl);
  gemm64<1,0><<<gP, blk, 0, stream>>>(xc, nullptr, 0, wot, ca_bo, t1,
                                      NROWS, DD, DD, DD, fl);
  ln_add_k<<<gL, blk, 0, stream>>>(x1, t1, ln2_g, ln2_b, x1, fl, 0);

  // ---- MLP (x2 == x1) ----
  transpose_k<<<dim3(FFD/64, DD/64), blk, 0, stream>>>(fc1_w, wt, DD, FFD, fl);  // fc1^T
  if (big_ws) {
    gemm64<1,1><<<gFC1, blk, 0, stream>>>(x1, nullptr, 0, wt, fc1_b, hb,
                                          NROWS, FFD, DD, FFD, fl);
    transpose_k<<<dim3(DD/64, FFD/64), blk, 0, stream>>>(fc2_w, wt, FFD, DD, fl); // fc2^T
    gemm64<1,0><<<gP, blk, 0, stream>>>(hb, nullptr, 0, wt, fc2_b, t1,
                                        NROWS, DD, FFD, DD, fl);
  } else {
    // qkv segs are free now: seg0 = fc2^T, seg1 = h-chunk [1024][4096]
    transpose_k<<<dim3(DD/64, FFD/64), blk, 0, stream>>>(fc2_w, qkv, FFD, DD, fl); // fc2^T
    bf16_t* hchunk = qkv + SEG;
    for (int c = 0; c < 4; ++c) {
      gemm64<1,1><<<dim3(FFD/128, 16), blk, 0, stream>>>(x1 + (size_t)c*1024*DD, nullptr, 0, wt,
                                                         fc1_b, hchunk, 1024, FFD, DD, FFD, fl);
      gemm64<1,0><<<dim3(DD/128, 16), blk, 0, stream>>>(hchunk, nullptr, 0, qkv, fc2_b,
                                                        t1 + (size_t)c*1024*DD, 1024, DD, FFD, DD, fl);
    }
  }
  ln_add_k<<<gL, blk, 0, stream>>>(x1, t1, ln3_g, ln3_b, d_out, fl, 1);
}